// Round 1
// baseline (1000.747 us; speedup 1.0000x reference)
//
#include <hip/hip_runtime.h>
#include <float.h>

#define K_CODES 1024
#define DIM 64
#define T_LEN 8192
#define B_N 16
#define N_TOK (B_N * T_LEN)   // 131072

// One thread per token. Score(k) = ||e_k||^2 - 2*x.e_k  (x_sq dropped: uniform per token).
__global__ __launch_bounds__(256, 2)
void vq_argmin_kernel(const float* __restrict__ in,
                      const float* __restrict__ cb,
                      float* __restrict__ out) {
    __shared__ float esq[K_CODES];

    const int tid = threadIdx.x;

    // Per-block e_sq precompute into LDS: 4 codes per thread, vectorized reads.
    for (int k = tid; k < K_CODES; k += 256) {
        const float* row = cb + (size_t)k * DIM;
        float s = 0.0f;
        #pragma unroll
        for (int d = 0; d < DIM; d += 4) {
            float4 v = *reinterpret_cast<const float4*>(row + d);
            s = fmaf(v.x, v.x, s);
            s = fmaf(v.y, v.y, s);
            s = fmaf(v.z, v.z, s);
            s = fmaf(v.w, v.w, s);
        }
        esq[k] = s;
    }
    __syncthreads();

    const int n = blockIdx.x * 256 + tid;   // token id
    const int b = n >> 13;                  // n / 8192
    const int t = n & 8191;                 // n % 8192

    // Load token vector (coalesced: lane stride 1 in t), pre-scale by -2.
    const float* xin = in + ((size_t)b * DIM) * T_LEN + t;
    float xm2[DIM];
    #pragma unroll
    for (int d = 0; d < DIM; ++d)
        xm2[d] = -2.0f * xin[(size_t)d * T_LEN];

    float best = FLT_MAX;
    int bidx = 0;

    // Main loop: 4 codes at a time for ILP; codebook address is wave-uniform
    // -> scalar (s_load) path, SMEM issue port, leaves VALU slots for FMAs.
    for (int k = 0; k < K_CODES; k += 4) {
        const float* c0 = cb + (size_t)k * DIM;
        float a0 = esq[k + 0];
        float a1 = esq[k + 1];
        float a2 = esq[k + 2];
        float a3 = esq[k + 3];
        #pragma unroll 16
        for (int d = 0; d < DIM; ++d) {
            const float x = xm2[d];
            a0 = fmaf(x, c0[d + 0 * DIM], a0);
            a1 = fmaf(x, c0[d + 1 * DIM], a1);
            a2 = fmaf(x, c0[d + 2 * DIM], a2);
            a3 = fmaf(x, c0[d + 3 * DIM], a3);
        }
        // Strict < with ascending k preserves argmin first-occurrence tie-break.
        if (a0 < best) { best = a0; bidx = k + 0; }
        if (a1 < best) { best = a1; bidx = k + 1; }
        if (a2 < best) { best = a2; bidx = k + 2; }
        if (a3 < best) { best = a3; bidx = k + 3; }
    }

    // Epilogue: gather winning codebook row (divergent loads, L2-hot; 256 KB table),
    // store coalesced in (B, D, T) layout; index as float.
    const float* crow = cb + (size_t)bidx * DIM;
    float* outv = out + ((size_t)b * DIM) * T_LEN + t;
    #pragma unroll
    for (int d = 0; d < DIM; ++d)
        outv[(size_t)d * T_LEN] = crow[d];

    out[(size_t)N_TOK * DIM + n] = (float)bidx;
}

extern "C" void kernel_launch(void* const* d_in, const int* in_sizes, int n_in,
                              void* d_out, int out_size, void* d_ws, size_t ws_size,
                              hipStream_t stream) {
    const float* in = (const float*)d_in[0];   // (16, 64, 8192) fp32
    const float* cb = (const float*)d_in[1];   // (1024, 64) fp32
    float* out = (float*)d_out;                // 8388608 floats + 131072 index-floats

    vq_argmin_kernel<<<dim3(N_TOK / 256), dim3(256), 0, stream>>>(in, cb, out);
}

// Round 2
// 153.785 us; speedup vs baseline: 6.5074x; 6.5074x over previous
//
#include <hip/hip_runtime.h>
#include <float.h>

#define K_CODES 1024
#define DIM 64
#define T_LEN 8192
#define N_TOK 131072          // 16 * 8192 tokens
#define LO_SCALE 2048.0f
#define LO_INV   (1.0f / 2048.0f)

typedef _Float16 half8 __attribute__((ext_vector_type(8)));   // 4 VGPRs: MFMA A/B frag
typedef float    f32x4 __attribute__((ext_vector_type(4)));   // MFMA C/D frag

// ---------------- prep: codebook fp32 -> f16 hi/lo split + e_sq ----------------
__global__ void vq_prep(const float* __restrict__ cb,
                        _Float16* __restrict__ whi,
                        _Float16* __restrict__ wlo,
                        float* __restrict__ wesq) {
    const int code = blockIdx.x * 256 + threadIdx.x;   // grid 4 x 256
    const float* row = cb + (size_t)code * DIM;
    float s = 0.0f;
    #pragma unroll
    for (int d0 = 0; d0 < DIM; d0 += 4) {
        float4 v = *reinterpret_cast<const float4*>(row + d0);
        float x[4] = {v.x, v.y, v.z, v.w};
        #pragma unroll
        for (int j = 0; j < 4; ++j) {
            float xx = x[j];
            _Float16 h = (_Float16)xx;
            _Float16 l = (_Float16)((xx - (float)h) * LO_SCALE);  // (xx - h) exact in fp32
            whi[(size_t)code * DIM + d0 + j] = h;
            wlo[(size_t)code * DIM + d0 + j] = l;
            s = fmaf(xx, xx, s);
        }
    }
    wesq[code] = s;
}

// ---------------- main: fused split-f16 GEMM + argmin + gather ----------------
// Wave = 64 tokens (4 m-tiles of 16). Block = 4 waves = 256 tokens. Grid = 512.
__global__ __launch_bounds__(256, 2)
void vq_main(const float* __restrict__ in,
             const float* __restrict__ cb,
             const _Float16* __restrict__ whi,
             const _Float16* __restrict__ wlo,
             const float* __restrict__ wesq,
             float* __restrict__ out) {
    __shared__ float esq_s[K_CODES];
    __shared__ int   idx_s[256];

    const int tid  = threadIdx.x;
    const int wave = tid >> 6;
    const int lane = tid & 63;
    const int lo4  = lane & 15;   // code residue (C col) / token residue (A m)
    const int quad = lane >> 4;   // selects k-offset in A/B frags; token-row group in C

    for (int k = tid; k < K_CODES; k += 256) esq_s[k] = wesq[k];
    __syncthreads();

    const int strip = (blockIdx.x * 4 + wave) * 64;  // token base (64-aligned, one b)
    const int b  = strip >> 13;
    const int t0 = strip & 8191;

    // ---- A fragments: X[token][d] -> f16 hi/lo, register-resident ----
    // A layout (16x16x32): m = lane&15, k = quad*8 + j (+ s*32)
    const float* xin = in + (size_t)b * DIM * T_LEN + t0;
    half8 a_hi[4][2], a_lo[4][2];
    #pragma unroll
    for (int mt = 0; mt < 4; ++mt) {
        #pragma unroll
        for (int s = 0; s < 2; ++s) {
            #pragma unroll
            for (int j = 0; j < 8; ++j) {
                const int d = s * 32 + quad * 8 + j;
                float x = xin[(size_t)d * T_LEN + mt * 16 + lo4];
                _Float16 h = (_Float16)x;
                _Float16 l = (_Float16)((x - (float)h) * LO_SCALE);
                a_hi[mt][s][j] = h;
                a_lo[mt][s][j] = l;
            }
        }
    }

    // ---- running argmin state: slot i = mt*4 + r -> token strip + mt*16 + quad*4 + r
    float best[16];
    int   bidx[16];
    #pragma unroll
    for (int i = 0; i < 16; ++i) { best[i] = FLT_MAX; bidx[i] = 0; }

    // B frag bases: code = ct*16 + lo4; element = code*64 + s*32 + quad*8
    const _Float16* hbase = whi + (size_t)lo4 * DIM + quad * 8;
    const _Float16* lbase = wlo + (size_t)lo4 * DIM + quad * 8;

    // prefetch ct = 0
    half8 cbh0 = *(const half8*)(hbase);
    half8 cbh1 = *(const half8*)(hbase + 32);
    half8 cbl0 = *(const half8*)(lbase);
    half8 cbl1 = *(const half8*)(lbase + 32);
    float cesq = esq_s[lo4];

    for (int ct = 0; ct < 64; ++ct) {
        // software prefetch ct+1 (clamped; redundant last load is harmless)
        const int nct = (ct < 63) ? (ct + 1) : 63;
        const size_t noff = (size_t)nct * 16 * DIM;
        half8 nbh0 = *(const half8*)(hbase + noff);
        half8 nbh1 = *(const half8*)(hbase + noff + 32);
        half8 nbl0 = *(const half8*)(lbase + noff);
        half8 nbl1 = *(const half8*)(lbase + noff + 32);
        float nesq = esq_s[nct * 16 + lo4];

        const int code = ct * 16 + lo4;
        #pragma unroll
        for (int mt = 0; mt < 4; ++mt) {
            f32x4 acc1 = {0.f, 0.f, 0.f, 0.f};   // x_hi . e_hi
            f32x4 acc2 = {0.f, 0.f, 0.f, 0.f};   // scaled cross terms (x2048)
            acc1 = __builtin_amdgcn_mfma_f32_16x16x32_f16(a_hi[mt][0], cbh0, acc1, 0, 0, 0);
            acc1 = __builtin_amdgcn_mfma_f32_16x16x32_f16(a_hi[mt][1], cbh1, acc1, 0, 0, 0);
            acc2 = __builtin_amdgcn_mfma_f32_16x16x32_f16(a_lo[mt][0], cbh0, acc2, 0, 0, 0);
            acc2 = __builtin_amdgcn_mfma_f32_16x16x32_f16(a_lo[mt][1], cbh1, acc2, 0, 0, 0);
            acc2 = __builtin_amdgcn_mfma_f32_16x16x32_f16(a_hi[mt][0], cbl0, acc2, 0, 0, 0);
            acc2 = __builtin_amdgcn_mfma_f32_16x16x32_f16(a_hi[mt][1], cbl1, acc2, 0, 0, 0);
            #pragma unroll
            for (int r = 0; r < 4; ++r) {
                float dot = fmaf(acc2[r], LO_INV, acc1[r]);
                float sc  = fmaf(dot, -2.0f, cesq);       // ||e||^2 - 2 x.e
                const int i = mt * 4 + r;
                bool lt = sc < best[i];                    // strict <: first occurrence wins
                best[i] = lt ? sc : best[i];
                bidx[i] = lt ? code : bidx[i];
            }
        }
        cbh0 = nbh0; cbh1 = nbh1; cbl0 = nbl0; cbl1 = nbl1; cesq = nesq;
    }

    // ---- cross-lane merge over the 16 code-residue lanes (xor on low 4 bits) ----
    #pragma unroll
    for (int i = 0; i < 16; ++i) {
        float s = best[i];
        int  ix = bidx[i];
        #pragma unroll
        for (int off = 1; off < 16; off <<= 1) {
            float s2 = __shfl_xor(s, off, 64);
            int  ix2 = __shfl_xor(ix, off, 64);
            bool take = (s2 < s) || (s2 == s && ix2 < ix);  // tie -> lower index (np argmin)
            s  = take ? s2 : s;
            ix = take ? ix2 : ix;
        }
        if (lo4 == 0) {
            // token_local = mt*16 + quad*4 + r,  mt = i>>2, r = i&3
            idx_s[wave * 64 + (i >> 2) * 16 + quad * 4 + (i & 3)] = ix;
        }
    }
    __syncthreads();

    // ---- epilogue: gather exact fp32 codebook row, coalesced store ----
    const int my_idx = idx_s[wave * 64 + lane];
    out[(size_t)N_TOK * DIM + strip + lane] = (float)my_idx;   // index output

    const float* crow = cb + (size_t)my_idx * DIM;
    float* outv = out + (size_t)b * DIM * T_LEN + t0 + lane;
    #pragma unroll
    for (int d0 = 0; d0 < DIM; d0 += 4) {
        float4 v = *reinterpret_cast<const float4*>(crow + d0);  // L2-hot gather
        outv[(size_t)(d0 + 0) * T_LEN] = v.x;
        outv[(size_t)(d0 + 1) * T_LEN] = v.y;
        outv[(size_t)(d0 + 2) * T_LEN] = v.z;
        outv[(size_t)(d0 + 3) * T_LEN] = v.w;
    }
}

extern "C" void kernel_launch(void* const* d_in, const int* in_sizes, int n_in,
                              void* d_out, int out_size, void* d_ws, size_t ws_size,
                              hipStream_t stream) {
    const float* in = (const float*)d_in[0];   // (16, 64, 8192) fp32
    const float* cb = (const float*)d_in[1];   // (1024, 64) fp32
    float* out = (float*)d_out;

    _Float16* whi = (_Float16*)d_ws;                    // 128 KB
    _Float16* wlo = whi + (size_t)K_CODES * DIM;        // 128 KB
    float*   wesq = (float*)(wlo + (size_t)K_CODES * DIM);  // 4 KB

    vq_prep<<<dim3(K_CODES / 256), dim3(256), 0, stream>>>(cb, whi, wlo, wesq);
    vq_main<<<dim3(N_TOK / 256), dim3(256), 0, stream>>>(in, cb, whi, wlo, wesq, out);
}

// Round 3
// 149.851 us; speedup vs baseline: 6.6783x; 1.0263x over previous
//
#include <hip/hip_runtime.h>
#include <float.h>

#define K_CODES 1024
#define DIM 64
#define T_LEN 8192
#define N_TOK 131072          // 16 * 8192 tokens
#define LO_SCALE 2048.0f
#define LO_INV   (1.0f / 2048.0f)

typedef _Float16 half8 __attribute__((ext_vector_type(8)));   // 4 VGPRs: MFMA A/B frag
typedef _Float16 half4 __attribute__((ext_vector_type(4)));   // 8B coalesced store
typedef float    f32x4 __attribute__((ext_vector_type(4)));   // MFMA C/D frag

// ---------------- prep: codebook fp32 -> f16 hi/lo split + e_sq ----------------
// One thread per (code, dim-quad): 16384 threads = 64 blocks. 8B coalesced stores
// (round-2 prep used 4 blocks + scalar 2B stores w/ 128B stride: ~60 us. This: ~3 us.)
__global__ void vq_prep(const float* __restrict__ cb,
                        _Float16* __restrict__ whi,
                        _Float16* __restrict__ wlo,
                        float* __restrict__ wesq) {
    const int t = blockIdx.x * 256 + threadIdx.x;   // 0..16383
    const int code = t >> 4;
    const int q    = t & 15;                         // dim quad: dims q*4..q*4+3

    float4 v = *reinterpret_cast<const float4*>(cb + (size_t)code * DIM + q * 4);
    float x[4] = {v.x, v.y, v.z, v.w};
    half4 h, l;
    float psum = 0.0f;
    #pragma unroll
    for (int j = 0; j < 4; ++j) {
        _Float16 hh = (_Float16)x[j];
        h[j] = hh;
        l[j] = (_Float16)((x[j] - (float)hh) * LO_SCALE);   // (x - h) exact in fp32
        psum = fmaf(x[j], x[j], psum);
    }
    *reinterpret_cast<half4*>(whi + (size_t)code * DIM + q * 4) = h;
    *reinterpret_cast<half4*>(wlo + (size_t)code * DIM + q * 4) = l;

    // e_sq: reduce over the 16 contiguous lanes of this code
    #pragma unroll
    for (int off = 1; off < 16; off <<= 1)
        psum += __shfl_xor(psum, off, 64);
    if (q == 0) wesq[code] = psum;
}

// ---------------- main: fused split-f16 GEMM + argmin + gather ----------------
// Wave = 64 tokens (4 m-tiles of 16). Block = 4 waves. Grid = 512 (8 waves/CU).
// A holds -2x (f16 hi/lo split); acc1 is MFMA-C-initialized with ||e||^2, so
// score = ||e||^2 - 2 x.e = fmaf(acc2, 1/2048, acc1). Two acc sets ping-pong:
// argmin of set ct-1 overlaps MFMAs of set ct (breaks the per-iter MFMA->VALU chain).
__global__ __launch_bounds__(256, 2)
void vq_main(const float* __restrict__ in,
             const float* __restrict__ cb,
             const _Float16* __restrict__ whi,
             const _Float16* __restrict__ wlo,
             const float* __restrict__ wesq,
             float* __restrict__ out) {
    __shared__ float esq_s[K_CODES];
    __shared__ int   idx_s[256];

    const int tid  = threadIdx.x;
    const int wave = tid >> 6;
    const int lane = tid & 63;
    const int lo4  = lane & 15;   // code residue (C col) / token residue (A m)
    const int quad = lane >> 4;   // k-offset selector in A/B frags; token-row group in C

    for (int k = tid; k < K_CODES; k += 256) esq_s[k] = wesq[k];
    __syncthreads();

    const int strip = (blockIdx.x * 4 + wave) * 64;  // token base (64-aligned, one b)
    const int b  = strip >> 13;
    const int t0 = strip & 8191;

    // ---- A fragments: -2 * X[token][d] -> f16 hi/lo, register-resident ----
    // A layout (16x16x32): m = lane&15, k = quad*8 + j (+ s*32)
    const float* xin = in + (size_t)b * DIM * T_LEN + t0;
    half8 a_hi[4][2], a_lo[4][2];
    #pragma unroll
    for (int mt = 0; mt < 4; ++mt) {
        #pragma unroll
        for (int s = 0; s < 2; ++s) {
            #pragma unroll
            for (int j = 0; j < 8; ++j) {
                const int d = s * 32 + quad * 8 + j;
                float x = -2.0f * xin[(size_t)d * T_LEN + mt * 16 + lo4];
                _Float16 h = (_Float16)x;
                a_hi[mt][s][j] = h;
                a_lo[mt][s][j] = (_Float16)((x - (float)h) * LO_SCALE);
            }
        }
    }

    // ---- running argmin state: slot i = mt*4 + r -> token strip + mt*16 + quad*4 + r
    float best[16];
    int   bidx[16];
    #pragma unroll
    for (int i = 0; i < 16; ++i) { best[i] = FLT_MAX; bidx[i] = 0; }

    // B frag base: code = ct*16 + lo4; element offset = code*64 + s*32 + quad*8
    const _Float16* hbase = whi + (size_t)lo4 * DIM + quad * 8;
    const _Float16* lbase = wlo + (size_t)lo4 * DIM + quad * 8;

    half8 beh0, beh1, bel0, bel1;   // B even-ct buffer
    half8 boh0, boh1, bol0, bol1;   // B odd-ct buffer
    float ese, eso;
    f32x4 accA1[4], accA2[4], accB1[4], accB2[4];

    auto load_b = [&](int ct, half8& h0, half8& h1, half8& l0, half8& l1, float& es) {
        const size_t off = (size_t)ct * 16 * DIM;
        h0 = *(const half8*)(hbase + off);
        h1 = *(const half8*)(hbase + off + 32);
        l0 = *(const half8*)(lbase + off);
        l1 = *(const half8*)(lbase + off + 32);
        es = esq_s[ct * 16 + lo4];
    };
    auto mfma_step = [&](f32x4* a1, f32x4* a2, const half8& h0, const half8& h1,
                         const half8& l0, const half8& l1, float cesq) {
        #pragma unroll
        for (int mt = 0; mt < 4; ++mt) {
            f32x4 c1 = {cesq, cesq, cesq, cesq};  // ||e||^2 folded into C input
            f32x4 c2 = {0.f, 0.f, 0.f, 0.f};
            c1 = __builtin_amdgcn_mfma_f32_16x16x32_f16(a_hi[mt][0], h0, c1, 0, 0, 0);
            c1 = __builtin_amdgcn_mfma_f32_16x16x32_f16(a_hi[mt][1], h1, c1, 0, 0, 0);
            c2 = __builtin_amdgcn_mfma_f32_16x16x32_f16(a_lo[mt][0], h0, c2, 0, 0, 0);
            c2 = __builtin_amdgcn_mfma_f32_16x16x32_f16(a_lo[mt][1], h1, c2, 0, 0, 0);
            c2 = __builtin_amdgcn_mfma_f32_16x16x32_f16(a_hi[mt][0], l0, c2, 0, 0, 0);
            c2 = __builtin_amdgcn_mfma_f32_16x16x32_f16(a_hi[mt][1], l1, c2, 0, 0, 0);
            a1[mt] = c1;
            a2[mt] = c2;
        }
    };
    auto argmin_step = [&](const f32x4* a1, const f32x4* a2, int code) {
        #pragma unroll
        for (int mt = 0; mt < 4; ++mt) {
            #pragma unroll
            for (int r = 0; r < 4; ++r) {
                float sc = fmaf(a2[mt][r], LO_INV, a1[mt][r]);
                const int i = mt * 4 + r;
                bool lt = sc < best[i];          // strict <: first occurrence wins
                best[i] = lt ? sc : best[i];
                bidx[i] = lt ? code : bidx[i];
            }
        }
    };

    // software pipeline: MFMA(ct) overlaps argmin(ct-1)
    load_b(0, beh0, beh1, bel0, bel1, ese);
    load_b(1, boh0, boh1, bol0, bol1, eso);
    mfma_step(accA1, accA2, beh0, beh1, bel0, bel1, ese);                 // ct = 0
    for (int p = 1; p <= 31; ++p) {
        load_b(2 * p, beh0, beh1, bel0, bel1, ese);                       // prefetch even
        mfma_step(accB1, accB2, boh0, boh1, bol0, bol1, eso);             // ct = 2p-1
        argmin_step(accA1, accA2, (2 * p - 2) * 16 + lo4);                // ct = 2p-2
        load_b(2 * p + 1, boh0, boh1, bol0, bol1, eso);                   // prefetch odd
        mfma_step(accA1, accA2, beh0, beh1, bel0, bel1, ese);             // ct = 2p
        argmin_step(accB1, accB2, (2 * p - 1) * 16 + lo4);                // ct = 2p-1
    }
    mfma_step(accB1, accB2, boh0, boh1, bol0, bol1, eso);                 // ct = 63
    argmin_step(accA1, accA2, 62 * 16 + lo4);
    argmin_step(accB1, accB2, 63 * 16 + lo4);

    // ---- cross-lane merge over the 16 code-residue lanes (xor on low 4 bits) ----
    #pragma unroll
    for (int i = 0; i < 16; ++i) {
        float s = best[i];
        int  ix = bidx[i];
        #pragma unroll
        for (int off = 1; off < 16; off <<= 1) {
            float s2 = __shfl_xor(s, off, 64);
            int  ix2 = __shfl_xor(ix, off, 64);
            bool take = (s2 < s) || (s2 == s && ix2 < ix);  // tie -> lower index
            s  = take ? s2 : s;
            ix = take ? ix2 : ix;
        }
        if (lo4 == 0) {
            // token_local = mt*16 + quad*4 + r,  mt = i>>2, r = i&3
            idx_s[wave * 64 + (i >> 2) * 16 + quad * 4 + (i & 3)] = ix;
        }
    }
    __syncthreads();

    // ---- epilogue: gather exact fp32 codebook row, coalesced store ----
    const int my_idx = idx_s[wave * 64 + lane];
    out[(size_t)N_TOK * DIM + strip + lane] = (float)my_idx;   // index output

    const float* crow = cb + (size_t)my_idx * DIM;
    float* outv = out + (size_t)b * DIM * T_LEN + t0 + lane;
    #pragma unroll
    for (int d0 = 0; d0 < DIM; d0 += 4) {
        float4 v = *reinterpret_cast<const float4*>(crow + d0);  // L2-hot gather
        outv[(size_t)(d0 + 0) * T_LEN] = v.x;
        outv[(size_t)(d0 + 1) * T_LEN] = v.y;
        outv[(size_t)(d0 + 2) * T_LEN] = v.z;
        outv[(size_t)(d0 + 3) * T_LEN] = v.w;
    }
}

extern "C" void kernel_launch(void* const* d_in, const int* in_sizes, int n_in,
                              void* d_out, int out_size, void* d_ws, size_t ws_size,
                              hipStream_t stream) {
    const float* in = (const float*)d_in[0];   // (16, 64, 8192) fp32
    const float* cb = (const float*)d_in[1];   // (1024, 64) fp32
    float* out = (float*)d_out;

    _Float16* whi = (_Float16*)d_ws;                        // 128 KB
    _Float16* wlo = whi + (size_t)K_CODES * DIM;            // 128 KB
    float*   wesq = (float*)(wlo + (size_t)K_CODES * DIM);  // 4 KB

    vq_prep<<<dim3(K_CODES * 16 / 256), dim3(256), 0, stream>>>(cb, whi, wlo, wesq);
    vq_main<<<dim3(N_TOK / 256), dim3(256), 0, stream>>>(in, cb, whi, wlo, wesq, out);
}